// Round 6
// baseline (411.395 us; speedup 1.0000x reference)
//
#include <hip/hip_runtime.h>
#include <hip/hip_bf16.h>
#include <math.h>

#define Bv 4
#define Sv 2048
#define Dv 1024
#define Hv 16
#define HD 64
#define NEGV (-1.0e9f)
#define QSCALE 0.1803368867f   // 0.125 * log2(e)

typedef __attribute__((ext_vector_type(8))) short bf16x8;   // 8 bf16 = 16 B
typedef __attribute__((ext_vector_type(4))) short s16x4;    // 4 bf16 = 8 B
typedef __attribute__((ext_vector_type(4))) float f32x4;    // MFMA C/D

// 2-op round-to-nearest bf16 (adds 0x8000 to magnitude; no NaN/inf inputs here)
__device__ __forceinline__ short f2bf(float f) {
    return (short)((__float_as_uint(f) + 0x8000u) >> 16);
}

__device__ __forceinline__ void glds16(const void* g, void* l) {
    __builtin_amdgcn_global_load_lds(
        (const __attribute__((address_space(1))) void*)g,
        (__attribute__((address_space(3))) void*)l, 16, 0, 0);
}

// ---------------------------------------------------------------------------
// fp32 -> bf16 bulk convert, up to 2 tensors (blockIdx.y selects).
// ---------------------------------------------------------------------------
__global__ __launch_bounds__(256) void cvt2(const float* __restrict__ X0,
                                            unsigned short* __restrict__ Y0,
                                            const float* __restrict__ X1,
                                            unsigned short* __restrict__ Y1) {
    const float* X = blockIdx.y ? X1 : X0;
    unsigned short* Y = blockIdx.y ? Y1 : Y0;
    const size_t i = ((size_t)blockIdx.x * 256 + threadIdx.x) * 8;
    const float4 a = *(const float4*)&X[i];
    const float4 b = *(const float4*)&X[i + 4];
    bf16x8 o = {f2bf(a.x), f2bf(a.y), f2bf(a.z), f2bf(a.w),
                f2bf(b.x), f2bf(b.y), f2bf(b.z), f2bf(b.w)};
    *(bf16x8*)&Y[i] = o;
}

// ---------------------------------------------------------------------------
// fp32 W [K=1024][N=1024] -> bf16 (W*scale)^T [N][K]; up to 2 jobs (z).
// ---------------------------------------------------------------------------
__global__ __launch_bounds__(256) void transpose_w2(const float* __restrict__ W0,
                                                    unsigned short* __restrict__ T0o,
                                                    float s0,
                                                    const float* __restrict__ W1,
                                                    unsigned short* __restrict__ T1o,
                                                    float s1) {
    const float* W = blockIdx.z ? W1 : W0;
    unsigned short* WT = blockIdx.z ? T1o : T0o;
    const float sc = blockIdx.z ? s1 : s0;
    __shared__ float T[64][65];
    const int t = threadIdx.x;
    const int n0 = blockIdx.x * 64, k0 = blockIdx.y * 64;
    #pragma unroll
    for (int i = 0; i < 4; ++i) {
        const int k = (t >> 4) + 16 * i;
        const int nc = (t & 15) * 4;
        const float4 v = *(const float4*)&W[(size_t)(k0 + k) * 1024 + n0 + nc];
        T[k][nc + 0] = v.x; T[k][nc + 1] = v.y;
        T[k][nc + 2] = v.z; T[k][nc + 3] = v.w;
    }
    __syncthreads();
    const int n = t >> 2, kc = (t & 3) * 16;
    #pragma unroll
    for (int j4 = 0; j4 < 4; ++j4) {
        s16x4 o;
        #pragma unroll
        for (int jj = 0; jj < 4; ++jj) o[jj] = f2bf(T[kc + j4 * 4 + jj][n] * sc);
        *(s16x4*)&WT[(size_t)(n0 + n) * 1024 + k0 + kc + j4 * 4] = o;
    }
}

// ---------------------------------------------------------------------------
// m97-structure GEMM core: C = X[MxK](bf16) @ W + bias*bscale, W as bf16 W^T.
// 128x128 tile, BK=32, 4 waves, 4x4 MFMA/wave, glds16 both operands.
// PERM=0: fp32 [M,N]. PERM=1: bf16 [B,H,S,64]. PERM=2: bf16 V^T [BH][64][S].
// ---------------------------------------------------------------------------
template <int PERM>
__device__ __forceinline__ void gemm_core(const unsigned short* __restrict__ X,
                                          const unsigned short* __restrict__ WT,
                                          const float* __restrict__ bias,
                                          float bscale, void* __restrict__ Cv,
                                          int M, int N, int K) {
    __shared__ short As[128 * 32];
    __shared__ short Bs[128 * 32];

    const int t = threadIdx.x;
    const int lane = t & 63, w = t >> 6;
    const int l15 = lane & 15, quad = lane >> 4;
    const int m0 = blockIdx.y * 128, n0 = blockIdx.x * 128;
    const int wm = (w >> 1) * 64, wn = (w & 1) * 64;

    f32x4 acc[4][4];
    #pragma unroll
    for (int mi = 0; mi < 4; ++mi)
        #pragma unroll
        for (int ni = 0; ni < 4; ++ni) acc[mi][ni] = (f32x4){0.f, 0.f, 0.f, 0.f};

    const int srow = lane >> 2;
    const int skc = (lane & 3) * 8;

    for (int k0 = 0; k0 < K; k0 += 32) {
        #pragma unroll
        for (int i = 0; i < 2; ++i) {
            const int seg = w * 2 + i;
            const int row = seg * 16 + srow;
            glds16(&WT[(size_t)(n0 + row) * K + k0 + skc], &Bs[seg * 512]);
            glds16(&X[(size_t)(m0 + row) * K + k0 + skc], &As[seg * 512]);
        }
        __syncthreads();

        bf16x8 afr[4], bfr[4];
        #pragma unroll
        for (int mi = 0; mi < 4; ++mi)
            afr[mi] = *(const bf16x8*)&As[(wm + mi * 16 + l15) * 32 + quad * 8];
        #pragma unroll
        for (int ni = 0; ni < 4; ++ni)
            bfr[ni] = *(const bf16x8*)&Bs[(wn + ni * 16 + l15) * 32 + quad * 8];
        #pragma unroll
        for (int mi = 0; mi < 4; ++mi)
            #pragma unroll
            for (int ni = 0; ni < 4; ++ni)
                acc[mi][ni] = __builtin_amdgcn_mfma_f32_16x16x32_bf16(
                    afr[mi], bfr[ni], acc[mi][ni], 0, 0, 0);
        __syncthreads();
    }

    #pragma unroll
    for (int mi = 0; mi < 4; ++mi) {
        #pragma unroll
        for (int ni = 0; ni < 4; ++ni) {
            const int col = n0 + wn + ni * 16 + l15;
            const float bsv = bias[col] * bscale;
            if constexpr (PERM == 2) {
                const int r0 = m0 + wm + mi * 16 + quad * 4;
                const int bb = r0 / Sv, s = r0 % Sv;
                const int hh = col >> 6, d = col & 63;
                s16x4 ov = {f2bf(acc[mi][ni][0] + bsv), f2bf(acc[mi][ni][1] + bsv),
                            f2bf(acc[mi][ni][2] + bsv), f2bf(acc[mi][ni][3] + bsv)};
                *(s16x4*)&((unsigned short*)Cv)[(((size_t)bb * Hv + hh) * 64 + d) * Sv + s] = ov;
            } else {
                #pragma unroll
                for (int r = 0; r < 4; ++r) {
                    const int row = m0 + wm + mi * 16 + quad * 4 + r;
                    const float vv = acc[mi][ni][r] + bsv;
                    if constexpr (PERM == 0) {
                        ((float*)Cv)[(size_t)row * N + col] = vv;
                    } else {
                        const int bb = row / Sv, s = row % Sv;
                        const int hh = col >> 6, d = col & 63;
                        ((unsigned short*)Cv)[((((size_t)bb * Hv + hh) * Sv + s) << 6) + d] =
                            (unsigned short)f2bf(vv);
                    }
                }
            }
        }
    }
}

__global__ __launch_bounds__(256) void gemm_qk(const unsigned short* Xq,
                                               const unsigned short* WTq,
                                               const float* bq, float sq,
                                               unsigned short* Cq,
                                               const unsigned short* Xk,
                                               const unsigned short* WTk,
                                               const float* bk,
                                               unsigned short* Ck,
                                               int M, int N, int K) {
    const bool z = blockIdx.z != 0;
    gemm_core<1>(z ? Xk : Xq, z ? WTk : WTq, z ? bk : bq, z ? 1.0f : sq,
                 z ? Ck : Cq, M, N, K);
}

__global__ __launch_bounds__(256) void gemm_v(const unsigned short* X,
                                              const unsigned short* WT,
                                              const float* bias,
                                              unsigned short* C,
                                              int M, int N, int K) {
    gemm_core<2>(X, WT, bias, 1.0f, C, M, N, K);
}

__global__ __launch_bounds__(256) void gemm_o(const unsigned short* X,
                                              const unsigned short* WT,
                                              const float* bias, float* C,
                                              int M, int N, int K) {
    gemm_core<0>(X, WT, bias, 1.0f, C, M, N, K);
}

// ---------------------------------------------------------------------------
// Flash attention, S^T form, exp2 path (Q pre-scaled by 0.125*log2e).
// 1D grid: idx = qt*nbh + hb (hb fastest -> same-head q-tiles share XCD
// under round-robin %8). 256 thr = 4 waves; wave w owns q-rows [w*32,+32).
// Q,K in [BH][S][64]; V^T in [BH][64][S]; out [rows][H*64] bf16.
// Sl stride 76 (152 B): P-store ~2-way (free); Kl/Vl stride 72.
// ---------------------------------------------------------------------------
__global__ __launch_bounds__(256) void attn_mfma(const unsigned short* __restrict__ Q,
                                                 const unsigned short* __restrict__ Kg,
                                                 const unsigned short* __restrict__ VT,
                                                 const int* __restrict__ mask,
                                                 unsigned short* __restrict__ O,
                                                 int nbh) {
    __shared__ short Kl[64 * 72];    // [kk][d]
    __shared__ short Vl[64 * 72];    // [dv][kk]
    __shared__ short Sl[128 * 76];   // [qrow][kk]
    __shared__ float Mk[64];

    const int t = threadIdx.x;
    const int lane = t & 63, w = t >> 6;
    const int l15 = lane & 15, quad = lane >> 4;
    const int bidx = blockIdx.x;
    const int hb = bidx % nbh;
    const int q0 = (bidx / nbh) * 128;
    const int b = hb >> 4, h = hb & 15;
    const size_t kvb = (size_t)hb * Sv * 64;
    const size_t vtb = (size_t)hb * 64 * Sv;

    bf16x8 qf[2][2];
    #pragma unroll
    for (int ni = 0; ni < 2; ++ni) {
        const size_t qa = kvb + (size_t)(q0 + w * 32 + ni * 16 + l15) * 64 + quad * 8;
        qf[ni][0] = *(const bf16x8*)&Q[qa];
        qf[ni][1] = *(const bf16x8*)&Q[qa + 32];
    }

    float l_acc[2] = {0.f, 0.f};
    f32x4 oacc[2][4];
    #pragma unroll
    for (int mi = 0; mi < 2; ++mi)
        #pragma unroll
        for (int ni = 0; ni < 4; ++ni) oacc[mi][ni] = (f32x4){0.f, 0.f, 0.f, 0.f};

    const int srow = t >> 2, sch = (t & 3) * 16;

    for (int k0 = 0; k0 < Sv; k0 += 64) {
        __syncthreads();
        {
            const unsigned short* Ks = Kg + kvb + (size_t)k0 * 64;
            const bf16x8 a = *(const bf16x8*)&Ks[(size_t)srow * 64 + sch];
            const bf16x8 c = *(const bf16x8*)&Ks[(size_t)srow * 64 + sch + 8];
            *(bf16x8*)&Kl[srow * 72 + sch] = a;
            *(bf16x8*)&Kl[srow * 72 + sch + 8] = c;
            const unsigned short* Vs = VT + vtb + k0;
            const bf16x8 d = *(const bf16x8*)&Vs[(size_t)srow * Sv + sch];
            const bf16x8 e = *(const bf16x8*)&Vs[(size_t)srow * Sv + sch + 8];
            *(bf16x8*)&Vl[srow * 72 + sch] = d;
            *(bf16x8*)&Vl[srow * 72 + sch + 8] = e;
        }
        if (t < 64) Mk[t] = NEGV * (float)mask[(size_t)b * Sv + k0 + t];
        __syncthreads();

        // S^T = K·(Q*c)^T ; p = exp2(st + mk) (mask -> -1e9 -> 0)
        #pragma unroll
        for (int mi = 0; mi < 4; ++mi) {
            const bf16x8 kf0 = *(const bf16x8*)&Kl[(mi * 16 + l15) * 72 + quad * 8];
            const bf16x8 kf1 = *(const bf16x8*)&Kl[(mi * 16 + l15) * 72 + 32 + quad * 8];
            const float4 mk4 = *(const float4*)&Mk[mi * 16 + quad * 4];
            #pragma unroll
            for (int ni = 0; ni < 2; ++ni) {
                f32x4 st = (f32x4){0.f, 0.f, 0.f, 0.f};
                st = __builtin_amdgcn_mfma_f32_16x16x32_bf16(kf0, qf[ni][0], st, 0, 0, 0);
                st = __builtin_amdgcn_mfma_f32_16x16x32_bf16(kf1, qf[ni][1], st, 0, 0, 0);
                const float p0 = exp2f(st[0] + mk4.x);
                const float p1 = exp2f(st[1] + mk4.y);
                const float p2 = exp2f(st[2] + mk4.z);
                const float p3 = exp2f(st[3] + mk4.w);
                l_acc[ni] += (p0 + p1) + (p2 + p3);
                s16x4 pv = {f2bf(p0), f2bf(p1), f2bf(p2), f2bf(p3)};
                *(s16x4*)&Sl[(w * 32 + ni * 16 + l15) * 76 + mi * 16 + quad * 4] = pv;
            }
        }

        // O += P·V
        #pragma unroll
        for (int mi = 0; mi < 2; ++mi) {
            const bf16x8 pf0 = *(const bf16x8*)&Sl[(w * 32 + mi * 16 + l15) * 76 + quad * 8];
            const bf16x8 pf1 = *(const bf16x8*)&Sl[(w * 32 + mi * 16 + l15) * 76 + 32 + quad * 8];
            #pragma unroll
            for (int ni = 0; ni < 4; ++ni) {
                const bf16x8 vf0 = *(const bf16x8*)&Vl[(ni * 16 + l15) * 72 + quad * 8];
                const bf16x8 vf1 = *(const bf16x8*)&Vl[(ni * 16 + l15) * 72 + 32 + quad * 8];
                oacc[mi][ni] = __builtin_amdgcn_mfma_f32_16x16x32_bf16(pf0, vf0, oacc[mi][ni], 0, 0, 0);
                oacc[mi][ni] = __builtin_amdgcn_mfma_f32_16x16x32_bf16(pf1, vf1, oacc[mi][ni], 0, 0, 0);
            }
        }
    }

    #pragma unroll
    for (int mi = 0; mi < 2; ++mi) {
        float l = l_acc[mi];
        l += __shfl_xor(l, 16);
        l += __shfl_xor(l, 32);
        #pragma unroll
        for (int r = 0; r < 4; ++r) {
            const float lr = __shfl(l, quad * 4 + r, 64);
            const float inv = 1.0f / lr;
            const size_t row = (size_t)b * Sv + q0 + w * 32 + mi * 16 + quad * 4 + r;
            #pragma unroll
            for (int ni = 0; ni < 4; ++ni) {
                O[row * (Hv * HD) + h * HD + ni * 16 + l15] =
                    (unsigned short)f2bf(oacc[mi][ni][r] * inv);
            }
        }
    }
}

// ---------------------------------------------------------------------------
extern "C" void kernel_launch(void* const* d_in, const int* in_sizes, int n_in,
                              void* d_out, int out_size, void* d_ws, size_t ws_size,
                              hipStream_t stream) {
    const float* query = (const float*)d_in[0];
    const float* key   = (const float*)d_in[1];
    const float* value = (const float*)d_in[2];
    const int*   amask = (const int*)d_in[3];
    const float* wq = (const float*)d_in[4];
    const float* bq = (const float*)d_in[5];
    const float* wk = (const float*)d_in[6];
    const float* bk = (const float*)d_in[7];
    const float* wv = (const float*)d_in[8];
    const float* bv = (const float*)d_in[9];
    const float* wo = (const float*)d_in[10];
    const float* bo = (const float*)d_in[11];
    float* out = (float*)d_out;

    unsigned short* wsp = (unsigned short*)d_ws;
    dim3 bb(256);

    if (ws_size >= (size_t)64 * 1024 * 1024) {
        const size_t PBQ = (size_t)Bv * Hv * Sv * HD;  // 8,388,608 (16 MB)
        unsigned short* qb = wsp;
        unsigned short* kb = qb + PBQ;
        unsigned short* vb = kb + PBQ;
        unsigned short* ab = vb + PBQ;
        unsigned short* xk = (unsigned short*)d_out;   // Xk staging (16 MB of 32)
        unsigned short* wtq = vb;                       // 2 MB (vb dead until V-GEMM)
        unsigned short* wtk = vb + 1024 * 1024;
        unsigned short* wtv = (unsigned short*)d_out;  // after Xk consumed
        unsigned short* wto = qb;                       // after attn

        const int M = Bv * Sv;  // 8192

        // Q/K projections, batched
        cvt2<<<dim3(4096, 2), bb, 0, stream>>>(query, ab, key, xk);
        transpose_w2<<<dim3(16, 16, 2), bb, 0, stream>>>(wq, wtq, QSCALE, wk, wtk, 1.0f);
        gemm_qk<<<dim3(8, 64, 2), bb, 0, stream>>>(ab, wtq, bq, QSCALE, qb,
                                                   xk, wtk, bk, kb, M, 1024, 1024);

        // V projection -> V^T directly
        cvt2<<<dim3(4096, 1), bb, 0, stream>>>(value, ab, value, ab);
        transpose_w2<<<dim3(16, 16, 1), bb, 0, stream>>>(wv, wtv, 1.0f, wv, wtv, 1.0f);
        gemm_v<<<dim3(8, 64), bb, 0, stream>>>(ab, wtv, bv, vb, M, 1024, 1024);

        // Attention -> ab
        attn_mfma<<<dim3(16 * 64), bb, 0, stream>>>(qb, kb, vb, amask, ab, 64);

        // Output projection
        transpose_w2<<<dim3(16, 16, 1), bb, 0, stream>>>(wo, wto, 1.0f, wo, wto, 1.0f);
        gemm_o<<<dim3(8, 64), bb, 0, stream>>>(ab, wto, bo, out, M, 1024, 1024);
    } else {
        // Per-batch fallback (16 MB scratch): qb|kb|vb|ab at 4 MB each.
        const size_t PQ = (size_t)Hv * Sv * HD;  // 2,097,152
        unsigned short* qb = wsp;
        unsigned short* kb = qb + PQ;
        unsigned short* vb = kb + PQ;
        unsigned short* ab = vb + PQ;
        const int M = Sv;
        for (int b = 0; b < Bv; ++b) {
            const size_t xoff = (size_t)b * Sv * Dv;
            unsigned short* xk = (unsigned short*)(out + xoff);
            unsigned short* wtq = vb;
            unsigned short* wtk = vb + 1024 * 1024;
            unsigned short* wtv = xk;
            unsigned short* wto = qb;

            cvt2<<<dim3(1024, 2), bb, 0, stream>>>(query + xoff, ab, key + xoff, xk);
            transpose_w2<<<dim3(16, 16, 2), bb, 0, stream>>>(wq, wtq, QSCALE, wk, wtk, 1.0f);
            gemm_qk<<<dim3(8, 16, 2), bb, 0, stream>>>(ab, wtq, bq, QSCALE, qb,
                                                       xk, wtk, bk, kb, M, 1024, 1024);

            cvt2<<<dim3(1024, 1), bb, 0, stream>>>(value + xoff, ab, value + xoff, ab);
            transpose_w2<<<dim3(16, 16, 1), bb, 0, stream>>>(wv, wtv, 1.0f, wv, wtv, 1.0f);
            gemm_v<<<dim3(8, 16), bb, 0, stream>>>(ab, wtv, bv, vb, M, 1024, 1024);

            attn_mfma<<<dim3(16 * 16), bb, 0, stream>>>(qb, kb, vb, amask + (size_t)b * Sv,
                                                        ab, 16);

            transpose_w2<<<dim3(16, 16, 1), bb, 0, stream>>>(wo, wto, 1.0f, wo, wto, 1.0f);
            gemm_o<<<dim3(8, 16), bb, 0, stream>>>(ab, wto, bo, out + xoff, M, 1024, 1024);
        }
    }
}